// Round 6
// baseline (365.547 us; speedup 1.0000x reference)
//
#include <hip/hip_runtime.h>

#define M_DIM 4096
#define N_DIM 8192
#define K_DIM 2048
#define NGRP 16
#define GSZ 512
#define EPSV 1e-5f

#define NX (M_DIM * K_DIM)            // x elems  = 8388608
#define NW (N_DIM * K_DIM)            // W elems  = 16777216
#define NY ((size_t)M_DIM * N_DIM)    // y elems  = 33554432

typedef __attribute__((ext_vector_type(8))) short bf16x8;
typedef __attribute__((ext_vector_type(4))) float f32x4;
typedef __attribute__((ext_vector_type(4))) int   i32x4;
typedef __attribute__((ext_vector_type(8))) short shortx8;

__device__ __forceinline__ float b2f(short u) {
    union { unsigned u32; float f; } c;
    c.u32 = ((unsigned)(unsigned short)u) << 16;
    return c.f;
}

__device__ __forceinline__ short f2b(float f) {
    union { float f; unsigned u; } c; c.f = f;
    unsigned r = (c.u + 0x7fffu + ((c.u >> 16) & 1u)) >> 16;
    return (short)r;
}

// ---------------- fp32 -> bf16 bulk convert (x then W, contiguous dst) -------
__global__ __launch_bounds__(256) void convert_kernel(
    const float* __restrict__ x, const float* __restrict__ W,
    short* __restrict__ dst)
{
    const size_t base = ((size_t)blockIdx.x * 256 + threadIdx.x) * 32;
    const float* src = (base < NX) ? (x + base) : (W + (base - NX));
    f32x4 v[8];
#pragma unroll
    for (int c = 0; c < 8; ++c) v[c] = *(const f32x4*)(src + c * 4);
#pragma unroll
    for (int c = 0; c < 4; ++c) {
        shortx8 o;
#pragma unroll
        for (int j = 0; j < 4; ++j) {
            o[j]     = f2b(v[2 * c][j]);
            o[j + 4] = f2b(v[2 * c + 1][j]);
        }
        *(shortx8*)(dst + base + c * 8) = o;
    }
}

// ---------- 256x256 bf16 GEMM, asm-ds_read software pipeline -----------------
// C = A @ W^T, bf16 in/out. BM=BN=256, 512 thr = 8 waves (2Mx4N), per-wave
// output 128x64 (acc[8][4] f32x4 -> AGPR). Ring-4 of BK=32 slots = 128 KiB,
// 1 block/CU, 2 waves/SIMD. __launch_bounds__(512,2) -- NEVER (512,4): regs
// cap at 128 = acc alone -> scratch spill (round-3: 9x).
// Rounds 2/4/5 post-mortem: every barrier-phased variant measured
// MFMA(1242cy) + LDS(1152cy) ADDITIVE per subtile. Mechanism: MFMA issue
// occupies the wave for the whole cluster (2 waves/SIMD share the matrix
// pipe), so next-phase ds_reads are only issued after the cluster -> LDS pipe
// idles during MFMA and vice versa. Compiler-tracked ds_reads made the
// round-1 ping-pong fail: hipcc inserts its own conservative lgkmcnt drain
// before the cluster (opaque asm waits don't update its model).
// Fix: INLINE-ASM ds_read_b128 (compiler inserts no waits for them; rule 18:
// we place the single lgkmcnt(0)+sched_barrier guard exactly one subtile
// later). Per subtile t:
//   stage(t+2) 4xgll -> vmcnt(4) [stage(t+1) landed; counted, never 0 until
//   tail] -> lgkmcnt(0) [reads(t) done; they had cluster(t-1) to complete]
//   -> s_barrier [block-wide cert] -> issue 12 asm ds_read of subtile t+1
//   into ping-pong set -> sched_barrier -> 32 MFMA on cur set.
// LDS reads (1152cy) now run under the MFMA cluster (1242cy).
// Hazards: RAW reads(t+1) vs stage(t+1): vmcnt(4)+barrier at t. WAR
// stage(t+2) vs reads(t-2) of same slot: those completed at t-2's lgkm(0),
// block-wide at t-2's barrier, >=2 barriers earlier. Tail: t=62 vmcnt(0)
// certifies 63; t=63 guard only. Ping-pong = named sets, static idx (r20).
// LDS swizzle (zero-conflict, verified): physical 16B chunk
// p = c ^ ((row>>1)&3); pre-swizzled GLOBAL source + swizzled read chunk.
// Grid: plain 2D raster (FETCH 98 MB; round-4's XCD swizzle blew L2: 270 MB).
#define BKS 32
#define NTILES (K_DIM / BKS)   // 64 subtiles

__global__ __launch_bounds__(512, 2) void gemm256_bf16_kernel(
    const short* __restrict__ A, const short* __restrict__ W, short* __restrict__ C)
{
    __shared__ __align__(16) short lds[4 * 16384];   // 128 KiB, ring-4 x 32KB

    const int tid  = threadIdx.x;
    const int lane = tid & 63;
    const int wave = tid >> 6;
    const int wr   = wave >> 2;        // 0..1  (M)
    const int wc   = wave & 3;         // 0..3  (N)
    const int blockRow = blockIdx.y * 256;
    const int blockCol = blockIdx.x * 256;

    // staging: linear chunk q (0..1023) -> LDS slot q*16B (row=q>>2, p=q&3);
    // fetch global chunk c = p ^ ((row>>1)&3) = (q&3) ^ ((q>>3)&3).
    const int q0 = tid, q1 = tid + 512;
    const int sr0 = q0 >> 2, sc0 = (q0 & 3) ^ ((q0 >> 3) & 3);
    const int sr1 = q1 >> 2, sc1 = (q1 & 3) ^ ((q1 >> 3) & 3);
    const int offA0 = (blockRow + sr0) * K_DIM + sc0 * 8;
    const int offA1 = (blockRow + sr1) * K_DIM + sc1 * 8;
    const int offB0 = (blockCol + sr0) * K_DIM + sc0 * 8;
    const int offB1 = (blockCol + sr1) * K_DIM + sc1 * 8;

    // fragment reads: row = warpBase + i*16 + fr -> (row>>1)&3 == (fr>>1)&3,
    // logical chunk c = lane>>4, physical p = c ^ ((fr>>1)&3).
    const int fr    = lane & 15;
    const int pbyte = ((lane >> 4) ^ ((fr >> 1) & 3)) * 16;
    const int aBase = (wr * 128 + fr) * 64 + pbyte;   // byte off, +i*1024
    const int bBase = (wc * 64  + fr) * 64 + pbyte;   // byte off, +j*1024

    f32x4 acc[8][4] = {};
    i32x4 fA0[8], fB0[4], fA1[8], fB1[4];   // ping-pong fragment sets

    auto gll = [&](const short* g, short* l) {
        __builtin_amdgcn_global_load_lds(
            (const __attribute__((address_space(1))) void*)g,
            (__attribute__((address_space(3))) void*)l, 16, 0, 0);
    };
    auto stage4 = [&](int t) {
        short* dA = lds + (t & 3) * 16384;
        short* dB = dA + 8192;
        const int ko = t * BKS;
        gll(A + offA0 + ko, dA + q0 * 8);
        gll(W + offB0 + ko, dB + q0 * 8);
        gll(A + offA1 + ko, dA + q1 * 8);
        gll(W + offB1 + ko, dB + q1 * 8);
    };

    // 12 inline-asm ds_read_b128: compiler inserts NO waitcnt for these;
    // we guard consumption manually one subtile later (rule 18).
    auto ldfrags = [&](int t, i32x4 (&fa)[8], i32x4 (&fb)[4]) {
        unsigned vA = (unsigned)(__UINTPTR_TYPE__)
            (__attribute__((address_space(3))) short*)(lds + (t & 3) * 16384) + (unsigned)aBase;
        unsigned vB = (unsigned)(__UINTPTR_TYPE__)
            (__attribute__((address_space(3))) short*)(lds + (t & 3) * 16384 + 8192) + (unsigned)bBase;
        asm volatile("ds_read_b128 %0, %1 offset:0"    : "=v"(fa[0]) : "v"(vA));
        asm volatile("ds_read_b128 %0, %1 offset:1024" : "=v"(fa[1]) : "v"(vA));
        asm volatile("ds_read_b128 %0, %1 offset:2048" : "=v"(fa[2]) : "v"(vA));
        asm volatile("ds_read_b128 %0, %1 offset:3072" : "=v"(fa[3]) : "v"(vA));
        asm volatile("ds_read_b128 %0, %1 offset:4096" : "=v"(fa[4]) : "v"(vA));
        asm volatile("ds_read_b128 %0, %1 offset:5120" : "=v"(fa[5]) : "v"(vA));
        asm volatile("ds_read_b128 %0, %1 offset:6144" : "=v"(fa[6]) : "v"(vA));
        asm volatile("ds_read_b128 %0, %1 offset:7168" : "=v"(fa[7]) : "v"(vA));
        asm volatile("ds_read_b128 %0, %1 offset:0"    : "=v"(fb[0]) : "v"(vB));
        asm volatile("ds_read_b128 %0, %1 offset:1024" : "=v"(fb[1]) : "v"(vB));
        asm volatile("ds_read_b128 %0, %1 offset:2048" : "=v"(fb[2]) : "v"(vB));
        asm volatile("ds_read_b128 %0, %1 offset:3072" : "=v"(fb[3]) : "v"(vB));
    };

    auto domfma = [&](i32x4 (&fa)[8], i32x4 (&fb)[4]) {
        __builtin_amdgcn_s_setprio(1);
#pragma unroll
        for (int i = 0; i < 8; ++i)
#pragma unroll
            for (int j = 0; j < 4; ++j)
                acc[i][j] = __builtin_amdgcn_mfma_f32_16x16x32_bf16(
                    __builtin_bit_cast(bf16x8, fa[i]),
                    __builtin_bit_cast(bf16x8, fb[j]),
                    acc[i][j], 0, 0, 0);
        __builtin_amdgcn_s_setprio(0);
    };

    // mode 0: stage t+2 + vmcnt(4); mode 1 (t=62): vmcnt(0); mode 2 (t=63):
    // guard only, no barrier, no reads.
    auto iter = [&](int t, i32x4 (&ca)[8], i32x4 (&cb)[4],
                    i32x4 (&na)[8], i32x4 (&nb)[4], int mode) {
        if (mode == 0) {
            stage4(t + 2);
            asm volatile("s_waitcnt vmcnt(4)" ::: "memory");
        } else if (mode == 1) {
            asm volatile("s_waitcnt vmcnt(0)" ::: "memory");
        }
        asm volatile("s_waitcnt lgkmcnt(0)" ::: "memory");   // reads(t) done
        __builtin_amdgcn_sched_barrier(0);
        if (mode != 2) {
            __builtin_amdgcn_s_barrier();
            __builtin_amdgcn_sched_barrier(0);
            ldfrags(t + 1, na, nb);          // in flight under the cluster
            __builtin_amdgcn_sched_barrier(0);
        }
        domfma(ca, cb);
    };

    // prologue: stage 0,1; certify 0; rendezvous; preload frags(0).
    stage4(0); stage4(1);
    asm volatile("s_waitcnt vmcnt(4)" ::: "memory");
    __builtin_amdgcn_s_barrier();
    __builtin_amdgcn_sched_barrier(0);
    ldfrags(0, fA0, fB0);
    __builtin_amdgcn_sched_barrier(0);

    for (int t = 0; t < 62; t += 2) {
        iter(t,     fA0, fB0, fA1, fB1, 0);
        iter(t + 1, fA1, fB1, fA0, fB0, 0);
    }
    iter(62, fA0, fB0, fA1, fB1, 1);
    iter(63, fA1, fB1, fA0, fB0, 2);

    // C/D layout: col=lane&15, row=(lane>>4)*4+reg
    const int er = (lane >> 4) * 4;
    const int ec = lane & 15;
#pragma unroll
    for (int i = 0; i < 8; ++i) {
        const int rr = blockRow + wr * 128 + i * 16 + er;
#pragma unroll
        for (int j = 0; j < 4; ++j) {
            const int cc = blockCol + wc * 64 + j * 16 + ec;
#pragma unroll
            for (int r = 0; r < 4; ++r)
                C[(size_t)(rr + r) * N_DIM + cc] = f2b(acc[i][j][r]);
        }
    }
}

// ------------- GN epilogue: read bf16 y, +bias, groupnorm, silu*mw*silu, fp32 out
__global__ __launch_bounds__(256) void gn_silu_bf16_kernel(
    const short* __restrict__ Y,
    const float* __restrict__ bias,
    const float* __restrict__ gnw,
    const float* __restrict__ gnb,
    const float* __restrict__ mw,
    float* __restrict__ out)
{
    const int lane = threadIdx.x & 63;
    const int wave = threadIdx.x >> 6;
    const unsigned gid = blockIdx.x * 4u + wave;     // 65536 groups
    const unsigned row = gid >> 4;
    const unsigned grp = gid & 15;
    const int col = grp * GSZ + lane * 8;
    const size_t off = (size_t)row * N_DIM + col;

    bf16x8 v = *(const bf16x8*)(Y + off);
    f32x4 b0 = *(const f32x4*)(bias + col);
    f32x4 b1 = *(const f32x4*)(bias + col + 4);

    float y[8];
    float s = 0.f, s2 = 0.f;
#pragma unroll
    for (int j = 0; j < 8; ++j) {
        y[j] = b2f(v[j]) + (j < 4 ? b0[j] : b1[j - 4]);
        s  += y[j];
        s2 += y[j] * y[j];
    }
#pragma unroll
    for (int d = 1; d < 64; d <<= 1) {
        s  += __shfl_xor(s,  d, 64);
        s2 += __shfl_xor(s2, d, 64);
    }
    const float mean = s * (1.0f / GSZ);
    const float var  = s2 * (1.0f / GSZ) - mean * mean;
    const float inv  = rsqrtf(var + EPSV);

    f32x4 w0 = *(const f32x4*)(gnw + col);
    f32x4 w1 = *(const f32x4*)(gnw + col + 4);
    f32x4 g0 = *(const f32x4*)(gnb + col);
    f32x4 g1 = *(const f32x4*)(gnb + col + 4);
    f32x4 m0 = *(const f32x4*)(mw + col);
    f32x4 m1 = *(const f32x4*)(mw + col + 4);

    f32x4 o0, o1;
#pragma unroll
    for (int j = 0; j < 8; ++j) {
        float gwv = j < 4 ? w0[j] : w1[j - 4];
        float gbv = j < 4 ? g0[j] : g1[j - 4];
        float mwv = j < 4 ? m0[j] : m1[j - 4];
        float n  = (y[j] - mean) * inv * gwv + gbv;
        float s1 = n / (1.f + __expf(-n));
        float m  = s1 * mwv;
        float r  = m / (1.f + __expf(-m));
        if (j < 4) o0[j] = r; else o1[j - 4] = r;
    }
    *(f32x4*)(out + off)     = o0;
    *(f32x4*)(out + off + 4) = o1;
}

// ================== fallback path (round-2, known-good) ======================
__global__ __launch_bounds__(256) void gemm_bt_f32_kernel(
    const float* __restrict__ A, const float* __restrict__ W, float* __restrict__ C)
{
    __shared__ __align__(16) short ldsA[128 * 32];
    __shared__ __align__(16) short ldsB[128 * 32];

    const int tid  = threadIdx.x;
    const int lane = tid & 63;
    const int wave = tid >> 6;
    const int blockRow = blockIdx.y * 128;
    const int blockCol = blockIdx.x * 128;
    const int srow = tid >> 1;
    const int scol = (tid & 1) * 16;
    const int wm  = (wave >> 1) * 64;
    const int wn  = (wave & 1) * 64;
    const int fr  = lane & 15;
    const int fko = (lane >> 4) * 8;

    f32x4 acc[4][4] = {};
    const size_t aRowOff = (size_t)(blockRow + srow) * K_DIM;
    const size_t wRowOff = (size_t)(blockCol + srow) * K_DIM;

    for (int k0 = 0; k0 < K_DIM; k0 += 32) {
        f32x4 va0 = *(const f32x4*)(A + aRowOff + k0 + scol);
        f32x4 va1 = *(const f32x4*)(A + aRowOff + k0 + scol + 4);
        f32x4 va2 = *(const f32x4*)(A + aRowOff + k0 + scol + 8);
        f32x4 va3 = *(const f32x4*)(A + aRowOff + k0 + scol + 12);
        f32x4 vb0 = *(const f32x4*)(W + wRowOff + k0 + scol);
        f32x4 vb1 = *(const f32x4*)(W + wRowOff + k0 + scol + 4);
        f32x4 vb2 = *(const f32x4*)(W + wRowOff + k0 + scol + 8);
        f32x4 vb3 = *(const f32x4*)(W + wRowOff + k0 + scol + 12);
        bf16x8 a0, a1, b0, b1;
#pragma unroll
        for (int j = 0; j < 4; ++j) {
            a0[j] = f2b(va0[j]); a0[j + 4] = f2b(va1[j]);
            a1[j] = f2b(va2[j]); a1[j + 4] = f2b(va3[j]);
            b0[j] = f2b(vb0[j]); b0[j + 4] = f2b(vb1[j]);
            b1[j] = f2b(vb2[j]); b1[j + 4] = f2b(vb3[j]);
        }
        *(bf16x8*)(ldsA + srow * 32 + scol)     = a0;
        *(bf16x8*)(ldsA + srow * 32 + scol + 8) = a1;
        *(bf16x8*)(ldsB + srow * 32 + scol)     = b0;
        *(bf16x8*)(ldsB + srow * 32 + scol + 8) = b1;
        __syncthreads();

        bf16x8 af[4], bfv[4];
#pragma unroll
        for (int i = 0; i < 4; ++i) {
            af[i]  = *(const bf16x8*)(ldsA + (wm + i * 16 + fr) * 32 + fko);
            bfv[i] = *(const bf16x8*)(ldsB + (wn + i * 16 + fr) * 32 + fko);
        }
#pragma unroll
        for (int i = 0; i < 4; ++i)
#pragma unroll
            for (int j = 0; j < 4; ++j)
                acc[i][j] = __builtin_amdgcn_mfma_f32_16x16x32_bf16(
                    af[i], bfv[j], acc[i][j], 0, 0, 0);
        __syncthreads();
    }

    const int er = (lane >> 4) * 4;
    const int ec = lane & 15;
#pragma unroll
    for (int i = 0; i < 4; ++i) {
        const int r0 = blockRow + wm + i * 16 + er;
#pragma unroll
        for (int j = 0; j < 4; ++j) {
            const int c0 = blockCol + wn + j * 16 + ec;
#pragma unroll
            for (int r = 0; r < 4; ++r)
                C[(size_t)(r0 + r) * N_DIM + c0] = acc[i][j][r];
        }
    }
}

__global__ __launch_bounds__(256) void gn_silu_f32_kernel(
    float* __restrict__ Y,
    const float* __restrict__ bias,
    const float* __restrict__ gnw,
    const float* __restrict__ gnb,
    const float* __restrict__ mw)
{
    const int lane = threadIdx.x & 63;
    const int wave = threadIdx.x >> 6;
    const unsigned gid = blockIdx.x * 4u + wave;
    const unsigned row = gid >> 4;
    const unsigned grp = gid & 15;
    const int col = grp * GSZ + lane * 8;
    const size_t off = (size_t)row * N_DIM + col;

    f32x4 v0 = *(const f32x4*)(Y + off);
    f32x4 v1 = *(const f32x4*)(Y + off + 4);
    f32x4 b0 = *(const f32x4*)(bias + col);
    f32x4 b1 = *(const f32x4*)(bias + col + 4);

    float y[8];
    float s = 0.f, s2 = 0.f;
#pragma unroll
    for (int j = 0; j < 8; ++j) {
        y[j] = (j < 4 ? v0[j] + b0[j] : v1[j - 4] + b1[j - 4]);
        s += y[j]; s2 += y[j] * y[j];
    }
#pragma unroll
    for (int d = 1; d < 64; d <<= 1) {
        s  += __shfl_xor(s,  d, 64);
        s2 += __shfl_xor(s2, d, 64);
    }
    const float mean = s * (1.0f / GSZ);
    const float var  = s2 * (1.0f / GSZ) - mean * mean;
    const float inv  = rsqrtf(var + EPSV);

    f32x4 w0 = *(const f32x4*)(gnw + col);
    f32x4 w1 = *(const f32x4*)(gnw + col + 4);
    f32x4 g0 = *(const f32x4*)(gnb + col);
    f32x4 g1 = *(const f32x4*)(gnb + col + 4);
    f32x4 m0 = *(const f32x4*)(mw + col);
    f32x4 m1 = *(const f32x4*)(mw + col + 4);

    f32x4 o0, o1;
#pragma unroll
    for (int j = 0; j < 8; ++j) {
        float gwv = j < 4 ? w0[j] : w1[j - 4];
        float gbv = j < 4 ? g0[j] : g1[j - 4];
        float mwv = j < 4 ? m0[j] : m1[j - 4];
        float n  = (y[j] - mean) * inv * gwv + gbv;
        float s1 = n / (1.f + __expf(-n));
        float m  = s1 * mwv;
        float r  = m / (1.f + __expf(-m));
        if (j < 4) o0[j] = r; else o1[j - 4] = r;
    }
    *(f32x4*)(Y + off)     = o0;
    *(f32x4*)(Y + off + 4) = o1;
}

extern "C" void kernel_launch(void* const* d_in, const int* in_sizes, int n_in,
                              void* d_out, int out_size, void* d_ws, size_t ws_size,
                              hipStream_t stream)
{
    const float* x   = (const float*)d_in[0];
    const float* W   = (const float*)d_in[1];
    const float* b   = (const float*)d_in[2];
    const float* gnw = (const float*)d_in[3];
    const float* gnb = (const float*)d_in[4];
    const float* mw  = (const float*)d_in[5];
    float* out = (float*)d_out;

    // ws layout: xb[NX] | Wb[NW] | yb[NY]  (bf16 shorts) = 117,440,512 bytes
    const size_t need = ((size_t)NX + NW + NY) * sizeof(short);
    const int ngroups = M_DIM * NGRP;       // 65536

    if (ws_size >= need) {
        short* xb = (short*)d_ws;
        short* Wb = xb + NX;
        short* yb = Wb + NW;

        convert_kernel<<<(NX + NW) / (256 * 32), 256, 0, stream>>>(x, W, xb);
        dim3 g256(N_DIM / 256, M_DIM / 256);   // 32 x 16 = 512 blocks, plain raster
        gemm256_bf16_kernel<<<g256, 512, 0, stream>>>(xb, Wb, yb);
        gn_silu_bf16_kernel<<<ngroups / 4, 256, 0, stream>>>(yb, b, gnw, gnb, mw, out);
    } else {
        dim3 ggrid(N_DIM / 128, M_DIM / 128);
        gemm_bt_f32_kernel<<<ggrid, 256, 0, stream>>>(x, W, out);
        gn_silu_f32_kernel<<<ngroups / 4, 256, 0, stream>>>(out, b, gnw, gnb, mw);
    }
}